// Round 1
// baseline (74.922 us; speedup 1.0000x reference)
//
#include <hip/hip_runtime.h>

#define CIN 8
#define CH 8
#define HH 128
#define WW 192
#define HO 256
#define WO 384
#define NINST 256
#define OTY 64
#define OTX 96
#define LTY 34   // low-res rows needed per 64-row output tile (worst case 34)
#define LTX 50   // low-res cols needed per 96-col output tile (worst case 50)
#define NPIX (LTY*LTX)   // 1700

__global__ __launch_bounds__(256) void dynmask_fused(
    const float* __restrict__ feats,    // (2, 8, 128, 192)
    const float* __restrict__ params,   // (256, 169)
    const float* __restrict__ locs,     // (256, 2)  [x, y]
    const float* __restrict__ soi,      // (256,)
    const int*   __restrict__ im_inds,  // (256,)
    const int*   __restrict__ stride_p, // (1,)
    float* __restrict__ out)            // (256, 1, 256, 384)
{
    const int n  = blockIdx.z;
    const int ty = blockIdx.y;
    const int tx = blockIdx.x;
    const int t  = threadIdx.x;

    __shared__ float sW0[8][12];   // 10 used, padded to 12 for float4 aligned rows
    __shared__ float sW1[8][8];
    __shared__ float sW2[8];
    __shared__ float sB0[8];
    __shared__ float sB1[8];
    __shared__ float sB2;
    __shared__ float tile[LTY][LTX];

    // ---- stage params for this instance into LDS ----
    const float* p = params + n * 169;
    if (t < 169) {
        float v = p[t];
        if (t < 80)       { sW0[t / 10][t % 10] = v; }
        else if (t < 144) { int j = t - 80; sW1[j >> 3][j & 7] = v; }
        else if (t < 152) { sW2[t - 144] = v; }
        else if (t < 160) { sB0[t - 152] = v; }
        else if (t < 168) { sB1[t - 160] = v; }
        else              { sB2 = v; }
    }

    const int   stride  = *stride_p;            // uniform scalar load
    const float inv_soi = 1.0f / soi[n];
    const float loc_x   = locs[2 * n + 0];
    const float loc_y   = locs[2 * n + 1];
    const int   im      = im_inds[n];
    const float* fbase  = feats + im * (CIN * HH * WW);

    const float sy = 127.0f / 255.0f;   // (H-1)/(Ho-1), same fp32 value as reference
    const float sx = 191.0f / 383.0f;

    const int oy0 = ty * OTY;
    const int ox0 = tx * OTX;
    const int ly0 = (int)((float)oy0 * sy);   // floor (nonneg)
    const int lx0 = (int)((float)ox0 * sx);

    __syncthreads();

    // ---- compute low-res logit tile (34x50) into LDS ----
    // each thread evaluates 4 pixels per pass to amortize LDS weight reads
    for (int base = 0; base < NPIX; base += 1024) {
        int   idx[4];
        float xin[4][10];

        #pragma unroll
        for (int q = 0; q < 4; ++q) {
            int id = base + t + q * 256;
            if (id > NPIX - 1) id = NPIX - 1;   // duplicate eval, benign
            idx[q] = id;
            int r = id / LTX;
            int c = id - r * LTX;
            int gy = ly0 + r; if (gy > HH - 1) gy = HH - 1;
            int gx = lx0 + c; if (gx > WW - 1) gx = WW - 1;
            float px = (float)(gx * stride + (stride >> 1));
            float py = (float)(gy * stride + (stride >> 1));
            xin[q][0] = (loc_x - px) * inv_soi;
            xin[q][1] = (loc_y - py) * inv_soi;
            const float* fp = fbase + gy * WW + gx;
            #pragma unroll
            for (int c8 = 0; c8 < 8; ++c8)
                xin[q][2 + c8] = fp[c8 * (HH * WW)];
        }

        // layer 0: 10 -> 8, relu
        float h0[4][8];
        #pragma unroll
        for (int o = 0; o < 8; ++o) {
            float w[12];
            *(float4*)&w[0] = *(const float4*)&sW0[o][0];
            *(float4*)&w[4] = *(const float4*)&sW0[o][4];
            *(float2*)&w[8] = *(const float2*)&sW0[o][8];
            float b = sB0[o];
            #pragma unroll
            for (int q = 0; q < 4; ++q) {
                float a = b;
                #pragma unroll
                for (int c = 0; c < 10; ++c) a = fmaf(xin[q][c], w[c], a);
                h0[q][o] = fmaxf(a, 0.0f);
            }
        }

        // layer 1: 8 -> 8, relu
        float h1[4][8];
        #pragma unroll
        for (int o = 0; o < 8; ++o) {
            float w[8];
            *(float4*)&w[0] = *(const float4*)&sW1[o][0];
            *(float4*)&w[4] = *(const float4*)&sW1[o][4];
            float b = sB1[o];
            #pragma unroll
            for (int q = 0; q < 4; ++q) {
                float a = b;
                #pragma unroll
                for (int c = 0; c < 8; ++c) a = fmaf(h0[q][c], w[c], a);
                h1[q][o] = fmaxf(a, 0.0f);
            }
        }

        // layer 2: 8 -> 1
        {
            float w[8];
            *(float4*)&w[0] = *(const float4*)&sW2[0];
            *(float4*)&w[4] = *(const float4*)&sW2[4];
            float b = sB2;
            #pragma unroll
            for (int q = 0; q < 4; ++q) {
                float a = b;
                #pragma unroll
                for (int c = 0; c < 8; ++c) a = fmaf(h1[q][c], w[c], a);
                ((float*)tile)[idx[q]] = a;
            }
        }
    }

    __syncthreads();

    // ---- bilinear upsample (align_corners) from LDS tile to global ----
    float* obase = out + (size_t)n * (HO * WO);
    #pragma unroll 4
    for (int i = t; i < OTY * OTX; i += 256) {
        int yl = i / OTX;
        int xl = i - yl * OTX;
        int yo = oy0 + yl;
        int xo = ox0 + xl;
        float ysf = (float)yo * sy;
        float xsf = (float)xo * sx;
        int iy0 = (int)ysf;
        int ix0 = (int)xsf;
        float wy = ysf - (float)iy0;
        float wx = xsf - (float)ix0;
        int iy1 = iy0 + 1; if (iy1 > HH - 1) iy1 = HH - 1;
        int ix1 = ix0 + 1; if (ix1 > WW - 1) ix1 = WW - 1;
        int ry0 = iy0 - ly0, ry1 = iy1 - ly0;
        int cx0 = ix0 - lx0, cx1 = ix1 - lx0;
        float t00 = tile[ry0][cx0], t01 = tile[ry0][cx1];
        float t10 = tile[ry1][cx0], t11 = tile[ry1][cx1];
        float va = t00 + wy * (t10 - t00);
        float vb = t01 + wy * (t11 - t01);
        obase[yo * WO + xo] = va + wx * (vb - va);
    }
}

extern "C" void kernel_launch(void* const* d_in, const int* in_sizes, int n_in,
                              void* d_out, int out_size, void* d_ws, size_t ws_size,
                              hipStream_t stream) {
    const float* feats    = (const float*)d_in[0];
    const float* params   = (const float*)d_in[1];
    const float* locs     = (const float*)d_in[2];
    const float* soi      = (const float*)d_in[3];
    const int*   im_inds  = (const int*)d_in[4];
    // d_in[5] = fpn_levels (unused by reference math)
    const int*   stride_p = (const int*)d_in[6];
    float* out = (float*)d_out;

    dim3 grid(WO / OTX, HO / OTY, NINST);   // (4, 4, 256)
    dim3 block(256);
    hipLaunchKernelGGL(dynmask_fused, grid, block, 0, stream,
                       feats, params, locs, soi, im_inds, stride_p, out);
}

// Round 2
// 54.879 us; speedup vs baseline: 1.3652x; 1.3652x over previous
//
#include <hip/hip_runtime.h>

typedef float f32x4 __attribute__((ext_vector_type(4)));

#define HH 128
#define WW 192
#define HO 256
#define WO 384
#define NINST 256
#define OTY 16          // output rows per block
#define LTY 10          // low-res rows staged per block (16*127/255 + 2 < 10)
#define STRIPS 24       // 192 / 8 strips per low-res row
#define MLPT 240        // 24 strips * 10 rows

__global__ __launch_bounds__(256) void dynmask_fused(
    const float* __restrict__ feats,    // (2, 8, 128, 192)
    const float* __restrict__ params,   // (256, 169)
    const float* __restrict__ locs,     // (256, 2)  [x, y]
    const float* __restrict__ soi,      // (256,)
    const int*   __restrict__ im_inds,  // (256,)
    const int*   __restrict__ stride_p, // (1,)
    float* __restrict__ out)            // (256, 1, 256, 384)
{
    const int n   = blockIdx.z;
    const int t   = threadIdx.x;
    const int oy0 = blockIdx.y * OTY;

    __shared__ float tile[LTY][WW];   // 7680 B

    const float sy = 127.0f / 255.0f;
    const float sx = 191.0f / 383.0f;
    const int ly0 = (int)((float)oy0 * sy);

    // all of these are wave-uniform -> scalar loads / SGPRs
    const float* __restrict__ pw = params + n * 169;
    const int   stride  = *stride_p;
    const float inv_soi = 1.0f / soi[n];
    const float loc_x   = locs[2*n+0];
    const float loc_y   = locs[2*n+1];
    const float* fbase  = feats + im_inds[n] * (8*HH*WW);

    if (t < MLPT) {
        const int r  = t / STRIPS;            // 0..9 (compile-known divisor)
        const int c0 = (t - r*STRIPS) * 8;    // 0..184
        int gy = ly0 + r; if (gy > HH-1) gy = HH-1;
        const float* frow = fbase + gy*WW + c0;

        const float pyf   = (float)(gy*stride + (stride>>1));
        const float yrel  = (loc_y - pyf) * inv_soi;
        const float xr0   = (loc_x - (float)(c0*stride + (stride>>1))) * inv_soi;
        const float xstep = -(float)stride * inv_soi;

        #pragma unroll
        for (int g = 0; g < 2; ++g) {
            // 8 channels x 4 consecutive px, aligned float4 loads
            f32x4 f[8];
            #pragma unroll
            for (int ch = 0; ch < 8; ++ch)
                f[ch] = *(const f32x4*)(frow + ch*(HH*WW) + g*4);

            float xr[4];
            #pragma unroll
            for (int j = 0; j < 4; ++j)
                xr[j] = fmaf((float)(g*4+j), xstep, xr0);

            // layer 0: 10 -> 8, relu  (weights from SGPRs)
            float h0[4][8];
            #pragma unroll
            for (int o = 0; o < 8; ++o) {
                const float wxw = pw[o*10+0];
                const float wyw = pw[o*10+1];
                const float b0w = pw[152+o];
                #pragma unroll
                for (int j = 0; j < 4; ++j) {
                    float a = fmaf(xr[j], wxw, fmaf(yrel, wyw, b0w));
                    #pragma unroll
                    for (int ch = 0; ch < 8; ++ch)
                        a = fmaf(f[ch][j], pw[o*10+2+ch], a);
                    h0[j][o] = fmaxf(a, 0.0f);
                }
            }

            // layers 1+2 fused: h1 never materialized
            float res[4];
            #pragma unroll
            for (int j = 0; j < 4; ++j) res[j] = pw[168];
            #pragma unroll
            for (int o = 0; o < 8; ++o) {
                const float b1w = pw[160+o];
                const float w2w = pw[144+o];
                #pragma unroll
                for (int j = 0; j < 4; ++j) {
                    float a = b1w;
                    #pragma unroll
                    for (int c = 0; c < 8; ++c)
                        a = fmaf(h0[j][c], pw[80+o*8+c], a);
                    res[j] = fmaf(fmaxf(a, 0.0f), w2w, res[j]);
                }
            }

            f32x4 rv; rv[0]=res[0]; rv[1]=res[1]; rv[2]=res[2]; rv[3]=res[3];
            *(f32x4*)&tile[r][c0 + g*4] = rv;   // 16B-aligned
        }
    }

    __syncthreads();

    // ---- bilinear upsample: 16 x 384 outputs, float4 stores ----
    float* obase = out + (size_t)n * (HO*WO);
    #pragma unroll
    for (int k = 0; k < 6; ++k) {
        int v  = t + k*256;                  // 0..1535, exact
        int yl = (int)((unsigned)v / 96u);
        int xv = v - yl*96;
        int yo = oy0 + yl;
        int xo0 = xv*4;

        float ysf = (float)yo * sy;
        int iy0 = (int)ysf;
        float wy = ysf - (float)iy0;
        int iy1 = iy0 + 1; if (iy1 > HH-1) iy1 = HH-1;
        const float* r0 = tile[iy0 - ly0];
        const float* r1 = tile[iy1 - ly0];

        f32x4 resv;
        #pragma unroll
        for (int j = 0; j < 4; ++j) {
            int xo = xo0 + j;
            float xsf = (float)xo * sx;
            int ix0 = (int)xsf;
            float wxf = xsf - (float)ix0;
            int ix1 = ix0 + 1; if (ix1 > WW-1) ix1 = WW-1;
            float t00 = r0[ix0], t01 = r0[ix1];
            float t10 = r1[ix0], t11 = r1[ix1];
            float va = fmaf(wy, t10 - t00, t00);
            float vb = fmaf(wy, t11 - t01, t01);
            resv[j] = fmaf(wxf, vb - va, va);
        }
        *(f32x4*)(obase + yo*WO + xo0) = resv;
    }
}

extern "C" void kernel_launch(void* const* d_in, const int* in_sizes, int n_in,
                              void* d_out, int out_size, void* d_ws, size_t ws_size,
                              hipStream_t stream) {
    const float* feats    = (const float*)d_in[0];
    const float* params   = (const float*)d_in[1];
    const float* locs     = (const float*)d_in[2];
    const float* soi      = (const float*)d_in[3];
    const int*   im_inds  = (const int*)d_in[4];
    // d_in[5] = fpn_levels (folded into sizes_of_interest already)
    const int*   stride_p = (const int*)d_in[6];
    float* out = (float*)d_out;

    dim3 grid(1, HO / OTY, NINST);   // (1, 16, 256)
    dim3 block(256);
    hipLaunchKernelGGL(dynmask_fused, grid, block, 0, stream,
                       feats, params, locs, soi, im_inds, stride_p, out);
}